// Round 11
// baseline (506.816 us; speedup 1.0000x reference)
//
#include <hip/hip_runtime.h>
#include <math.h>

#define B_   8192
#define N_   68
#define FIN  2
#define F_   128
#define C_   16
#define E_   272

// d_out flat layout (fp32), reference tuple order:
#define OUT_OFF  0                              // [B,16,128]
#define ADJ_OFF  (B_*C_*F_)                     // [B,16,16]
#define LINK_IDX (ADJ_OFF + B_*C_*C_)
#define ENT_IDX  (LINK_IDX + 1)
#define POS_OFF  (ENT_IDX + 1)                  // [B,68,2]

// ws: [0,131072) partials (doubles, 8192*2)
//     [131072,+1364) csr ints
//     [133120,+131072) wcat bf16 (2 layers * 128 j * 256 k)
//     [264192,+20480) Ag bf16 [80][128] (graph multiplicity, zero rows/cols >= 68)
#define WS_CSR_OFF  131072
#define WS_W_OFF    133120
#define WS_AG_OFF   264192

typedef __attribute__((ext_vector_type(8))) short bf16x8;
typedef __attribute__((ext_vector_type(4))) float f32x4;

// XOR swizzles (T2). Row strides 512/256/192 B; XOR bits 4-5 only.
#define SWZ256(r, cb) (((r) * 256) + ((cb) ^ (((r) & 7) << 4)))
#define SWZ512(r, cb) (((r) * 512) + ((cb) ^ (((r) & 7) << 4)))
#define SWZH(r, cb)   (((r) * 192) + ((cb) ^ (((r) & 3) << 4)))
#define MFMA16(a, bb, c) __builtin_amdgcn_mfma_f32_16x16x32_bf16((a), (bb), (c), 0, 0, 0)

__device__ __forceinline__ short bf16_rne(float x) {
  unsigned u = __builtin_bit_cast(unsigned, x);
  u += 0x7FFFu + ((u >> 16) & 1u);
  return (short)(u >> 16);
}
__device__ __forceinline__ short4 pack4(f32x4 v) {
  short4 s;
  s.x = bf16_rne(v[0]); s.y = bf16_rne(v[1]); s.z = bf16_rne(v[2]); s.w = bf16_rne(v[3]);
  return s;
}

__global__ void prep_kernel(const int* __restrict__ edge_index,
                            const float* __restrict__ W2r, const float* __restrict__ W2o,
                            const float* __restrict__ W3r, const float* __restrict__ W3o,
                            int* __restrict__ csr, short* __restrict__ wcat,
                            short* __restrict__ agw) {
  int gid = blockIdx.x * blockDim.x + threadIdx.x;
  for (int e = gid; e < 2 * F_ * 256; e += gridDim.x * blockDim.x) {
    int layer = e >> 15, idx = e & 32767;
    int j = idx >> 8, k = idx & 255;
    const float* Wr = layer ? W3r : W2r;
    const float* Wo = layer ? W3o : W2o;
    float v = (k < F_) ? Wr[j * F_ + k] : Wo[j * F_ + (k - F_)];
    wcat[e] = bf16_rne(v);
  }
  __shared__ unsigned short cnt[80 * 128];
  __shared__ int src_s[E_], dst_s[E_], cc[N_], offs[N_ + 1];
  if (blockIdx.x == 0) {
    int t = threadIdx.x;
    for (int i = t; i < 80 * 128; i += blockDim.x) cnt[i] = 0;
    for (int e = t; e < E_; e += blockDim.x) { src_s[e] = edge_index[e]; dst_s[e] = edge_index[E_ + e]; }
    for (int n = t; n < N_; n += blockDim.x) cc[n] = 0;
    __syncthreads();
    if (t == 0) {
      for (int e = 0; e < E_; ++e) { cnt[dst_s[e] * 128 + src_s[e]]++; cc[dst_s[e]]++; }
      offs[0] = 0;
      for (int n = 0; n < N_; ++n) offs[n + 1] = offs[n] + cc[n];
      for (int n = 0; n < N_; ++n) cc[n] = offs[n];
      for (int e = 0; e < E_; ++e) { int d = dst_s[e]; csr[N_ + 1 + cc[d]++] = src_s[e]; }
      for (int n = 0; n <= N_; ++n) csr[n] = offs[n];
    }
    __syncthreads();
    for (int i = t; i < 80 * 128; i += blockDim.x) agw[i] = bf16_rne((float)cnt[i]);
  }
}

// One GraphConv layer: h' = relu(Ag*(h*Wr^T) + h*Wo^T + b). See round-10 notes.
__device__ __forceinline__ void layer_mfma(short* Hn, short* UT,
    const short* __restrict__ wl, const float* __restrict__ bias,
    const short* __restrict__ agw,
    int hinB, int houtB, int outT, int l15, int lg, int j0)
{
  bf16x8 Ar[4], Ao[4];
#pragma unroll
  for (int ks = 0; ks < 4; ++ks) {
    Ar[ks] = *(const bf16x8*)(wl + (j0 + l15) * 256 + ks * 32 + 8 * lg);
    Ao[ks] = *(const bf16x8*)(wl + (j0 + l15) * 256 + 128 + ks * 32 + 8 * lg);
  }
  f32x4 U0 = {0,0,0,0}, U1 = {0,0,0,0}, U2 = {0,0,0,0}, U3 = {0,0,0,0}, U4 = {0,0,0,0};
  f32x4 V0 = {0,0,0,0}, V1 = {0,0,0,0}, V2 = {0,0,0,0}, V3 = {0,0,0,0}, V4 = {0,0,0,0};
#define G1_(UN, VN, NT) do { \
  _Pragma("unroll") \
  for (int ks = 0; ks < 4; ++ks) { \
    bf16x8 b_ = *(const bf16x8*)((const char*)Hn + SWZ512((NT) * 16 + l15, hinB + ks * 64 + 16 * lg)); \
    UN = MFMA16(Ar[ks], b_, UN); \
    VN = MFMA16(Ao[ks], b_, VN); \
  } \
} while (0)
  G1_(U0, V0, 0); G1_(U1, V1, 1); G1_(U2, V2, 2); G1_(U3, V3, 3); G1_(U4, V4, 4);
#undef G1_
#define UTW_(UN, NT) do { \
  _Pragma("unroll") \
  for (int q = 0; q < 4; ++q) \
    *(short*)((char*)UT + SWZH(j0 + lg * 4 + q, ((NT) * 16 + l15) * 2)) = bf16_rne(UN[q]); \
} while (0)
  UTW_(U0, 0); UTW_(U1, 1); UTW_(U2, 2); UTW_(U3, 3); UTW_(U4, 4);
#undef UTW_
  bf16x8 aU[3];
#pragma unroll
  for (int ks = 0; ks < 3; ++ks)
    aU[ks] = *(const bf16x8*)((const char*)UT + SWZH(j0 + l15, ks * 64 + 16 * lg));
  float4 bv = *(const float4*)&bias[j0 + lg * 4];
#define G2_(VN, NT) do { \
  f32x4 acc = {0.f, 0.f, 0.f, 0.f}; \
  _Pragma("unroll") \
  for (int ks = 0; ks < 3; ++ks) \
    acc = MFMA16(aU[ks], *(const bf16x8*)(agw + ((NT) * 16 + l15) * 128 + ks * 32 + lg * 8), acc); \
  f32x4 v_; \
  v_[0] = fmaxf(acc[0] + VN[0] + bv.x, 0.f); \
  v_[1] = fmaxf(acc[1] + VN[1] + bv.y, 0.f); \
  v_[2] = fmaxf(acc[2] + VN[2] + bv.z, 0.f); \
  v_[3] = fmaxf(acc[3] + VN[3] + bv.w, 0.f); \
  if (!outT) { \
    *(short4*)((char*)Hn + SWZ512((NT) * 16 + l15, houtB + (j0 + lg * 4) * 2)) = pack4(v_); \
  } else { \
    _Pragma("unroll") \
    for (int q = 0; q < 4; ++q) \
      *(short*)((char*)UT + SWZH(j0 + lg * 4 + q, ((NT) * 16 + l15) * 2)) = bf16_rne(v_[q]); \
  } \
} while (0)
  G2_(V0, 0); G2_(V1, 1); G2_(V2, 2); G2_(V3, 3); G2_(V4, 4);
#undef G2_
}

// ========== main kernel: 3 layers + pooled out + adj pooling + losses ==========
__launch_bounds__(512, 4)
__global__ void main_kernel(
    const float* __restrict__ x, const float* __restrict__ adj, const float* __restrict__ s,
    const float* __restrict__ pos,
    const float* __restrict__ W1r, const float* __restrict__ W1o, const float* __restrict__ b1,
    const float* __restrict__ b2f, const float* __restrict__ b3f,
    const short* __restrict__ wcat, const short* __restrict__ agw,
    float* __restrict__ out, const int* __restrict__ csr, double* __restrict__ partials)
{
  __shared__ __align__(16) short Hn[80 * 256];    // [n]: bytes [0,256)=h_even, [256,512)=h_odd
  __shared__ __align__(16) short UT[128 * 96];    // U^T / h3^T; reused as AdjB after P7a
  __shared__ __align__(16) short ssmT[16 * 128];  // softmax(s)^T [c][n], zero-pad n>=68
  __shared__ __align__(16) short TT[16 * 128];    // (adj@S)^T [c][n], zero-pad n>=68
  __shared__ float xb[N_ * FIN], axb[N_ * FIN];
  __shared__ int offs[N_ + 1], srcs[E_];
  __shared__ double red[16];

  const int b = blockIdx.x, tid = threadIdx.x;
  const int lane = tid & 63, wave = tid >> 6;
  const int l15 = lane & 15, lg = lane >> 4;
  const int j0 = wave * 16;

  // ---- P0: fills + pad zeroing + softmax + adj reg-stage (issue early, use late) ----
  for (int i = tid; i < N_ + 1; i += 512) offs[i] = csr[i];
  for (int i = tid; i < E_; i += 512) srcs[i] = csr[N_ + 1 + i];
  for (int i = tid; i < N_ * FIN; i += 512) xb[i] = x[(size_t)b * N_ * FIN + i];
  // adj slice -> 10 named registers (T14: HBM latency hidden under layers compute)
  const float* adjb = &adj[(size_t)b * N_ * N_];
  float av0, av1, av2, av3, av4, av5, av6, av7, av8, av9;
#define ALD_(I) { int q_ = tid + 512 * I; av##I = (q_ < N_ * N_) ? adjb[q_] : 0.f; }
  ALD_(0) ALD_(1) ALD_(2) ALD_(3) ALD_(4) ALD_(5) ALD_(6) ALD_(7) ALD_(8) ALD_(9)
#undef ALD_
  float sadj2 = av0*av0 + av1*av1 + av2*av2 + av3*av3 + av4*av4
              + av5*av5 + av6*av6 + av7*av7 + av8*av8 + av9*av9;
  {
    int4 zz; zz.x = 0; zz.y = 0; zz.z = 0; zz.w = 0;
    for (int i = tid; i < 384; i += 512) {          // Hn rows 68-79 (both halves)
      int r = 68 + (i >> 5), cb = (i & 31) * 16;
      *(int4*)((char*)Hn + SWZ512(r, cb)) = zz;
    }
    long long z8 = 0;
    for (int i = tid; i < 128 * 2; i += 512) {      // UT cols [80,96)
      int r = i >> 1, cb = 160 + (i & 1) * 16;
      *(int4*)((char*)UT + SWZH(r, cb)) = zz;
    }
    for (int i = tid; i < 16 * 7; i += 512) {       // ssmT/TT cols [68,96)
      int r = i / 7, cb = 136 + (i % 7) * 8;
      *(long long*)((char*)ssmT + SWZ256(r, cb)) = z8;
      *(long long*)((char*)TT + SWZ256(r, cb)) = z8;
    }
  }
  float entPart = 0.f;
  if (tid < N_) {
    const float* srow = &s[((size_t)b * N_ + tid) * C_];
    float sv[16], ev[16];
    float mx = -1e30f;
#pragma unroll
    for (int c = 0; c < 16; ++c) { sv[c] = srow[c]; mx = fmaxf(mx, sv[c]); }
    float sum = 0.f;
#pragma unroll
    for (int c = 0; c < 16; ++c) { ev[c] = expf(sv[c] - mx); sum += ev[c]; }
    float inv = 1.f / sum, ps = 0.f;
#pragma unroll
    for (int c = 0; c < 16; ++c) {
      float pv = ev[c] * inv;
      ps += pv * sv[c];
      *(short*)((char*)ssmT + SWZ256(c, tid * 2)) = bf16_rne(pv);
    }
    entPart = (mx + logf(sum)) - ps;
  }
  for (int i = tid; i < N_ * FIN; i += 512)
    out[POS_OFF + (size_t)b * N_ * FIN + i] = pos[(size_t)b * N_ * FIN + i];
  __syncthreads();

  // ---- P1: layer-1 edge aggregation on [68,2] ----
  if (tid < N_) {
    float a0 = 0, a1 = 0;
    for (int e = offs[tid]; e < offs[tid + 1]; ++e) {
      int sr = srcs[e];
      a0 += xb[sr * 2]; a1 += xb[sr * 2 + 1];
    }
    axb[tid * 2] = a0; axb[tid * 2 + 1] = a1;
  }
  __syncthreads();

  // ---- P2: layer 1 (K=2, VALU) -> Hn h_even (b64, node-major only) ----
  {
    int f4 = (tid & 31) * 4;
    float4 R0 = *(const float4*)&W1r[f4 * 2], R1 = *(const float4*)&W1r[f4 * 2 + 4];
    float4 O0 = *(const float4*)&W1o[f4 * 2], O1 = *(const float4*)&W1o[f4 * 2 + 4];
    float4 Bv = *(const float4*)&b1[f4];
#pragma unroll
    for (int p = 0; p < 5; ++p) {
      int n = p * 16 + (tid >> 5);
      if (n < N_) {
        float a0 = axb[n * 2], a1 = axb[n * 2 + 1], x0 = xb[n * 2], x1 = xb[n * 2 + 1];
        f32x4 v;
        v[0] = fmaxf(a0 * R0.x + a1 * R0.y + x0 * O0.x + x1 * O0.y + Bv.x, 0.f);
        v[1] = fmaxf(a0 * R0.z + a1 * R0.w + x0 * O0.z + x1 * O0.w + Bv.y, 0.f);
        v[2] = fmaxf(a0 * R1.x + a1 * R1.y + x0 * O1.x + x1 * O1.y + Bv.z, 0.f);
        v[3] = fmaxf(a0 * R1.z + a1 * R1.w + x0 * O1.z + x1 * O1.w + Bv.w, 0.f);
        *(short4*)((char*)Hn + SWZ512(n, f4 * 2)) = pack4(v);
      }
    }
  }
  __syncthreads();

  // ---- L2: h2 = relu(Ag*(h1*W2r^T) + h1*W2o^T + b2) -> Hn h_odd ----
  layer_mfma(Hn, UT, wcat, b2f, agw, /*hinB*/0, /*houtB*/256, /*outT*/0, l15, lg, j0);
  __syncthreads();

  // ---- L3: h3 = relu(Ag*(h2*W3r^T) + h2*W3o^T + b3) -> UT (= h3^T) ----
  layer_mfma(Hn, UT, wcat + 32768, b3f, agw, /*hinB*/256, /*houtB*/0, /*outT*/1, l15, lg, j0);
  // no barrier: P7a reads only wave-local UT rows + ssmT (stable since P0)

  // ---- P7a: pooled out: outT[f][c] = sum_n h3T[f][n] * S[n][c] ----
  {
    f32x4 acc = {0.f, 0.f, 0.f, 0.f};
#pragma unroll
    for (int ks = 0; ks < 3; ++ks)
      acc = MFMA16(*(const bf16x8*)((const char*)UT + SWZH(j0 + l15, ks * 64 + 16 * lg)),
                   *(const bf16x8*)((const char*)ssmT + SWZ256(l15, ks * 64 + 16 * lg)), acc);
    float4 st; st.x = acc[0]; st.y = acc[1]; st.z = acc[2]; st.w = acc[3];
    *(float4*)&out[OUT_OFF + (size_t)b * C_ * F_ + l15 * F_ + j0 + lg * 4] = st;
  }
  __syncthreads();   // all waves done with UT -> safe to reuse as AdjB

  // ---- P8: AdjB (= UT space, SWZ256 [80][128]): zero pads + scatter from regs ----
  {
    long long z8 = 0;
    for (int i = tid; i < 1200; i += 512) {          // cols [68,128), rows 0-79
      int r = i / 15, cb = 136 + (i % 15) * 8;
      *(long long*)((char*)UT + SWZ256(r, cb)) = z8;
    }
    for (int i = tid; i < 204; i += 512) {           // rows 68-79, cols [0,68)
      int r = 68 + i / 17, cb = (i % 17) * 8;
      *(long long*)((char*)UT + SWZ256(r, cb)) = z8;
    }
#define AST_(I) { int q_ = tid + 512 * I; if (q_ < N_ * N_) { \
    int n_ = q_ / N_, m_ = q_ - n_ * N_; \
    *(short*)((char*)UT + SWZ256(n_, m_ * 2)) = bf16_rne(av##I); } }
    AST_(0) AST_(1) AST_(2) AST_(3) AST_(4) AST_(5) AST_(6) AST_(7) AST_(8) AST_(9)
#undef AST_
  }
  __syncthreads();

  // ---- P9: T = adj@S (waves 0-4) -> TT ; G = S^T S (wave 5) ----
  float g2Part = 0.f;
  if (wave < 5) {
    f32x4 acc = {0.f, 0.f, 0.f, 0.f};
#pragma unroll
    for (int ks = 0; ks < 3; ++ks)
      acc = MFMA16(*(const bf16x8*)((const char*)UT + SWZ256(wave * 16 + l15, ks * 64 + 16 * lg)),
                   *(const bf16x8*)((const char*)ssmT + SWZ256(l15, ks * 64 + 16 * lg)), acc);
#pragma unroll
    for (int r = 0; r < 4; ++r) {
      int n = wave * 16 + lg * 4 + r;
      if (n < N_) *(short*)((char*)TT + SWZ256(l15, n * 2)) = bf16_rne(acc[r]);
    }
  } else if (wave == 5) {
    f32x4 acc = {0.f, 0.f, 0.f, 0.f};
#pragma unroll
    for (int ks = 0; ks < 3; ++ks) {
      bf16x8 a = *(const bf16x8*)((const char*)ssmT + SWZ256(l15, ks * 64 + 16 * lg));
      acc = MFMA16(a, a, acc);
    }
#pragma unroll
    for (int r = 0; r < 4; ++r) g2Part += acc[r] * acc[r];
  }
  __syncthreads();

  // ---- P10: out_adj = S^T T (wave 0) + trace; losses ----
  float trPart = 0.f;
  if (wave == 0) {
    f32x4 acc = {0.f, 0.f, 0.f, 0.f};
#pragma unroll
    for (int ks = 0; ks < 3; ++ks)
      acc = MFMA16(*(const bf16x8*)((const char*)ssmT + SWZ256(l15, ks * 64 + 16 * lg)),
                   *(const bf16x8*)((const char*)TT + SWZ256(l15, ks * 64 + 16 * lg)), acc);
#pragma unroll
    for (int r = 0; r < 4; ++r) {
      int c = lg * 4 + r;
      out[ADJ_OFF + (size_t)b * 256 + c * 16 + l15] = acc[r];
      if (c == l15) trPart += acc[r];
    }
  }
  double lk = (double)sadj2 - 2.0 * (double)trPart + (double)g2Part;
  double en = (double)entPart;
  for (int o = 32; o > 0; o >>= 1) { lk += __shfl_down(lk, o); en += __shfl_down(en, o); }
  if ((tid & 63) == 0) { red[wave] = lk; red[8 + wave] = en; }
  __syncthreads();
  if (tid == 0) {
    double L = 0, En = 0;
    for (int w = 0; w < 8; ++w) { L += red[w]; En += red[8 + w]; }
    partials[2 * b] = L;
    partials[2 * b + 1] = En;
  }
}

__global__ void finalize_kernel(const double* __restrict__ partials, float* __restrict__ out) {
  __shared__ double red[16];
  int tid = threadIdx.x;
  double L = 0, En = 0;
  for (int i = tid; i < B_; i += 512) { L += partials[2 * i]; En += partials[2 * i + 1]; }
  for (int o = 32; o > 0; o >>= 1) { L += __shfl_down(L, o); En += __shfl_down(En, o); }
  if ((tid & 63) == 0) { red[tid >> 6] = L; red[8 + (tid >> 6)] = En; }
  __syncthreads();
  if (tid == 0) {
    double Ls = 0, Es = 0;
    for (int w = 0; w < 8; ++w) { Ls += red[w]; Es += red[8 + w]; }
    out[LINK_IDX] = (float)(sqrt(Ls) / (double)((size_t)B_ * N_ * N_));
    out[ENT_IDX] = (float)(Es / (double)((size_t)B_ * N_));
  }
}

extern "C" void kernel_launch(void* const* d_in, const int* in_sizes, int n_in,
                              void* d_out, int out_size, void* d_ws, size_t ws_size,
                              hipStream_t stream) {
  const float* x   = (const float*)d_in[0];
  const int*   ei  = (const int*)d_in[1];
  const float* adj = (const float*)d_in[2];
  const float* s   = (const float*)d_in[3];
  const float* pos = (const float*)d_in[4];
  const float* W1r = (const float*)d_in[5];
  const float* W1o = (const float*)d_in[6];
  const float* b1  = (const float*)d_in[7];
  const float* W2r = (const float*)d_in[8];
  const float* W2o = (const float*)d_in[9];
  const float* b2  = (const float*)d_in[10];
  const float* W3r = (const float*)d_in[11];
  const float* W3o = (const float*)d_in[12];
  const float* b3  = (const float*)d_in[13];

  float* out = (float*)d_out;
  double* partials = (double*)d_ws;
  int* csr = (int*)((char*)d_ws + WS_CSR_OFF);
  short* wcat = (short*)((char*)d_ws + WS_W_OFF);
  short* agw  = (short*)((char*)d_ws + WS_AG_OFF);

  prep_kernel<<<65, 512, 0, stream>>>(ei, W2r, W2o, W3r, W3o, csr, wcat, agw);
  main_kernel<<<B_, 512, 0, stream>>>(x, adj, s, pos, W1r, W1o, b1, b2, b3,
                                      wcat, agw, out, csr, partials);
  finalize_kernel<<<1, 512, 0, stream>>>(partials, out);
}

// Round 12
// 470.671 us; speedup vs baseline: 1.0768x; 1.0768x over previous
//
#include <hip/hip_runtime.h>
#include <math.h>

#define B_   8192
#define N_   68
#define FIN  2
#define F_   128
#define C_   16
#define E_   272

// d_out flat layout (fp32), reference tuple order:
#define OUT_OFF  0                              // [B,16,128]
#define ADJ_OFF  (B_*C_*F_)                     // [B,16,16]
#define LINK_IDX (ADJ_OFF + B_*C_*C_)
#define ENT_IDX  (LINK_IDX + 1)
#define POS_OFF  (ENT_IDX + 1)                  // [B,68,2]

// ws: [0,131072) partials (doubles, 8192*2)
//     [131072,+1364) csr ints
//     [133120,+131072) wcat bf16 (2 layers * 128 j * 256 k)
//     [264192,+20480) Ag bf16 [80][128] (graph multiplicity, zero rows/cols >= 68)
#define WS_CSR_OFF  131072
#define WS_W_OFF    133120
#define WS_AG_OFF   264192

typedef __attribute__((ext_vector_type(8))) short bf16x8;
typedef __attribute__((ext_vector_type(4))) float f32x4;

// XOR swizzles (T2). Row strides 512/256/192 B; XOR bits 4-5 only.
#define SWZ256(r, cb) (((r) * 256) + ((cb) ^ (((r) & 7) << 4)))
#define SWZ512(r, cb) (((r) * 512) + ((cb) ^ (((r) & 7) << 4)))
#define SWZH(r, cb)   (((r) * 192) + ((cb) ^ (((r) & 3) << 4)))
#define MFMA16(a, bb, c) __builtin_amdgcn_mfma_f32_16x16x32_bf16((a), (bb), (c), 0, 0, 0)

__device__ __forceinline__ short bf16_rne(float x) {
  unsigned u = __builtin_bit_cast(unsigned, x);
  u += 0x7FFFu + ((u >> 16) & 1u);
  return (short)(u >> 16);
}
__device__ __forceinline__ short4 pack4(f32x4 v) {
  short4 s;
  s.x = bf16_rne(v[0]); s.y = bf16_rne(v[1]); s.z = bf16_rne(v[2]); s.w = bf16_rne(v[3]);
  return s;
}

__global__ void prep_kernel(const int* __restrict__ edge_index,
                            const float* __restrict__ W2r, const float* __restrict__ W2o,
                            const float* __restrict__ W3r, const float* __restrict__ W3o,
                            int* __restrict__ csr, short* __restrict__ wcat,
                            short* __restrict__ agw) {
  int gid = blockIdx.x * blockDim.x + threadIdx.x;
  for (int e = gid; e < 2 * F_ * 256; e += gridDim.x * blockDim.x) {
    int layer = e >> 15, idx = e & 32767;
    int j = idx >> 8, k = idx & 255;
    const float* Wr = layer ? W3r : W2r;
    const float* Wo = layer ? W3o : W2o;
    float v = (k < F_) ? Wr[j * F_ + k] : Wo[j * F_ + (k - F_)];
    wcat[e] = bf16_rne(v);
  }
  __shared__ unsigned short cnt[80 * 128];
  __shared__ int src_s[E_], dst_s[E_], cc[N_], offs[N_ + 1];
  if (blockIdx.x == 0) {
    int t = threadIdx.x;
    for (int i = t; i < 80 * 128; i += blockDim.x) cnt[i] = 0;
    for (int e = t; e < E_; e += blockDim.x) { src_s[e] = edge_index[e]; dst_s[e] = edge_index[E_ + e]; }
    for (int n = t; n < N_; n += blockDim.x) cc[n] = 0;
    __syncthreads();
    if (t == 0) {
      for (int e = 0; e < E_; ++e) { cnt[dst_s[e] * 128 + src_s[e]]++; cc[dst_s[e]]++; }
      offs[0] = 0;
      for (int n = 0; n < N_; ++n) offs[n + 1] = offs[n] + cc[n];
      for (int n = 0; n < N_; ++n) cc[n] = offs[n];
      for (int e = 0; e < E_; ++e) { int d = dst_s[e]; csr[N_ + 1 + cc[d]++] = src_s[e]; }
      for (int n = 0; n <= N_; ++n) csr[n] = offs[n];
    }
    __syncthreads();
    for (int i = t; i < 80 * 128; i += blockDim.x) agw[i] = bf16_rne((float)cnt[i]);
  }
}

// One GraphConv layer: h' = relu(Ag*(h*Wr^T) + h*Wo^T + b). See round-10 notes.
__device__ __forceinline__ void layer_mfma(short* Hn, short* UT,
    const short* __restrict__ wl, const float* __restrict__ bias,
    const short* __restrict__ agw,
    int hinB, int houtB, int outT, int l15, int lg, int j0)
{
  bf16x8 Ar[4], Ao[4];
#pragma unroll
  for (int ks = 0; ks < 4; ++ks) {
    Ar[ks] = *(const bf16x8*)(wl + (j0 + l15) * 256 + ks * 32 + 8 * lg);
    Ao[ks] = *(const bf16x8*)(wl + (j0 + l15) * 256 + 128 + ks * 32 + 8 * lg);
  }
  f32x4 U0 = {0,0,0,0}, U1 = {0,0,0,0}, U2 = {0,0,0,0}, U3 = {0,0,0,0}, U4 = {0,0,0,0};
  f32x4 V0 = {0,0,0,0}, V1 = {0,0,0,0}, V2 = {0,0,0,0}, V3 = {0,0,0,0}, V4 = {0,0,0,0};
#define G1_(UN, VN, NT) do { \
  _Pragma("unroll") \
  for (int ks = 0; ks < 4; ++ks) { \
    bf16x8 b_ = *(const bf16x8*)((const char*)Hn + SWZ512((NT) * 16 + l15, hinB + ks * 64 + 16 * lg)); \
    UN = MFMA16(Ar[ks], b_, UN); \
    VN = MFMA16(Ao[ks], b_, VN); \
  } \
} while (0)
  G1_(U0, V0, 0); G1_(U1, V1, 1); G1_(U2, V2, 2); G1_(U3, V3, 3); G1_(U4, V4, 4);
#undef G1_
#define UTW_(UN, NT) do { \
  _Pragma("unroll") \
  for (int q = 0; q < 4; ++q) \
    *(short*)((char*)UT + SWZH(j0 + lg * 4 + q, ((NT) * 16 + l15) * 2)) = bf16_rne(UN[q]); \
} while (0)
  UTW_(U0, 0); UTW_(U1, 1); UTW_(U2, 2); UTW_(U3, 3); UTW_(U4, 4);
#undef UTW_
  bf16x8 aU[3];
#pragma unroll
  for (int ks = 0; ks < 3; ++ks)
    aU[ks] = *(const bf16x8*)((const char*)UT + SWZH(j0 + l15, ks * 64 + 16 * lg));
  float4 bv = *(const float4*)&bias[j0 + lg * 4];
#define G2_(VN, NT) do { \
  f32x4 acc = {0.f, 0.f, 0.f, 0.f}; \
  _Pragma("unroll") \
  for (int ks = 0; ks < 3; ++ks) \
    acc = MFMA16(aU[ks], *(const bf16x8*)(agw + ((NT) * 16 + l15) * 128 + ks * 32 + lg * 8), acc); \
  f32x4 v_; \
  v_[0] = fmaxf(acc[0] + VN[0] + bv.x, 0.f); \
  v_[1] = fmaxf(acc[1] + VN[1] + bv.y, 0.f); \
  v_[2] = fmaxf(acc[2] + VN[2] + bv.z, 0.f); \
  v_[3] = fmaxf(acc[3] + VN[3] + bv.w, 0.f); \
  if (!outT) { \
    *(short4*)((char*)Hn + SWZ512((NT) * 16 + l15, houtB + (j0 + lg * 4) * 2)) = pack4(v_); \
  } else { \
    _Pragma("unroll") \
    for (int q = 0; q < 4; ++q) \
      *(short*)((char*)UT + SWZH(j0 + lg * 4 + q, ((NT) * 16 + l15) * 2)) = bf16_rne(v_[q]); \
  } \
} while (0)
  G2_(V0, 0); G2_(V1, 1); G2_(V2, 2); G2_(V3, 3); G2_(V4, 4);
#undef G2_
}

// ================= Kernel A: 3 GraphConv layers + pooled out (round-10 verified) =================
__launch_bounds__(512, 4)
__global__ void layers_kernel(
    const float* __restrict__ x, const float* __restrict__ s,
    const float* __restrict__ W1r, const float* __restrict__ W1o, const float* __restrict__ b1,
    const float* __restrict__ b2f, const float* __restrict__ b3f,
    const short* __restrict__ wcat, const short* __restrict__ agw,
    float* __restrict__ out, const int* __restrict__ csr)
{
  __shared__ __align__(16) short Hn[80 * 256];    // [n]: bytes [0,256)=h_even, [256,512)=h_odd
  __shared__ __align__(16) short UT[128 * 96];    // U^T scratch; h3^T at the end
  __shared__ __align__(16) short ssmT[16 * 128];  // softmax(s)^T [c][n], zero-pad n>=68
  __shared__ float xb[N_ * FIN], axb[N_ * FIN];
  __shared__ int offs[N_ + 1], srcs[E_];

  const int b = blockIdx.x, tid = threadIdx.x;
  const int lane = tid & 63, wave = tid >> 6;
  const int l15 = lane & 15, lg = lane >> 4;
  const int j0 = wave * 16;

  // ---- P0: fills + pad zeroing + softmax ----
  for (int i = tid; i < N_ + 1; i += 512) offs[i] = csr[i];
  for (int i = tid; i < E_; i += 512) srcs[i] = csr[N_ + 1 + i];
  for (int i = tid; i < N_ * FIN; i += 512) xb[i] = x[(size_t)b * N_ * FIN + i];
  {
    int4 zz; zz.x = 0; zz.y = 0; zz.z = 0; zz.w = 0;
    for (int i = tid; i < 384; i += 512) {          // Hn rows 68-79 (both halves)
      int r = 68 + (i >> 5), cb = (i & 31) * 16;
      *(int4*)((char*)Hn + SWZ512(r, cb)) = zz;
    }
    long long z8 = 0;
    for (int i = tid; i < 128 * 2; i += 512) {      // UT cols [80,96)
      int r = i >> 1, cb = 160 + (i & 1) * 16;
      *(int4*)((char*)UT + SWZH(r, cb)) = zz;
    }
    for (int i = tid; i < 16 * 7; i += 512) {       // ssmT cols [68,96)
      int r = i / 7, cb = 136 + (i % 7) * 8;
      *(long long*)((char*)ssmT + SWZ256(r, cb)) = z8;
    }
  }
  if (tid < N_) {
    const float* srow = &s[((size_t)b * N_ + tid) * C_];
    float sv[16];
    float mx = -1e30f;
#pragma unroll
    for (int c = 0; c < 16; ++c) { sv[c] = srow[c]; mx = fmaxf(mx, sv[c]); }
    float sum = 0.f;
#pragma unroll
    for (int c = 0; c < 16; ++c) { sv[c] = expf(sv[c] - mx); sum += sv[c]; }
    float inv = 1.f / sum;
#pragma unroll
    for (int c = 0; c < 16; ++c)
      *(short*)((char*)ssmT + SWZ256(c, tid * 2)) = bf16_rne(sv[c] * inv);
  }
  __syncthreads();

  // ---- P1: layer-1 edge aggregation on [68,2] ----
  if (tid < N_) {
    float a0 = 0, a1 = 0;
    for (int e = offs[tid]; e < offs[tid + 1]; ++e) {
      int sr = srcs[e];
      a0 += xb[sr * 2]; a1 += xb[sr * 2 + 1];
    }
    axb[tid * 2] = a0; axb[tid * 2 + 1] = a1;
  }
  __syncthreads();

  // ---- P2: layer 1 (K=2, VALU) -> Hn h_even (b64, node-major only) ----
  {
    int f4 = (tid & 31) * 4;
    float4 R0 = *(const float4*)&W1r[f4 * 2], R1 = *(const float4*)&W1r[f4 * 2 + 4];
    float4 O0 = *(const float4*)&W1o[f4 * 2], O1 = *(const float4*)&W1o[f4 * 2 + 4];
    float4 Bv = *(const float4*)&b1[f4];
#pragma unroll
    for (int p = 0; p < 5; ++p) {
      int n = p * 16 + (tid >> 5);
      if (n < N_) {
        float a0 = axb[n * 2], a1 = axb[n * 2 + 1], x0 = xb[n * 2], x1 = xb[n * 2 + 1];
        f32x4 v;
        v[0] = fmaxf(a0 * R0.x + a1 * R0.y + x0 * O0.x + x1 * O0.y + Bv.x, 0.f);
        v[1] = fmaxf(a0 * R0.z + a1 * R0.w + x0 * O0.z + x1 * O0.w + Bv.y, 0.f);
        v[2] = fmaxf(a0 * R1.x + a1 * R1.y + x0 * O1.x + x1 * O1.y + Bv.z, 0.f);
        v[3] = fmaxf(a0 * R1.z + a1 * R1.w + x0 * O1.z + x1 * O1.w + Bv.w, 0.f);
        *(short4*)((char*)Hn + SWZ512(n, f4 * 2)) = pack4(v);
      }
    }
  }
  __syncthreads();

  // ---- L2: h2 = relu(Ag*(h1*W2r^T) + h1*W2o^T + b2) -> Hn h_odd ----
  layer_mfma(Hn, UT, wcat, b2f, agw, /*hinB*/0, /*houtB*/256, /*outT*/0, l15, lg, j0);
  __syncthreads();

  // ---- L3: h3 = relu(Ag*(h2*W3r^T) + h2*W3o^T + b3) -> UT (= h3^T) ----
  layer_mfma(Hn, UT, wcat + 32768, b3f, agw, /*hinB*/256, /*houtB*/0, /*outT*/1, l15, lg, j0);
  // no barrier: P7a reads only wave-local UT rows + ssmT (stable since P0)

  // ---- P7a: pooled out: outT[f][c] = sum_n h3T[f][n] * S[n][c] ----
  {
    f32x4 acc = {0.f, 0.f, 0.f, 0.f};
#pragma unroll
    for (int ks = 0; ks < 3; ++ks)
      acc = MFMA16(*(const bf16x8*)((const char*)UT + SWZH(j0 + l15, ks * 64 + 16 * lg)),
                   *(const bf16x8*)((const char*)ssmT + SWZ256(l15, ks * 64 + 16 * lg)), acc);
    float4 st; st.x = acc[0]; st.y = acc[1]; st.z = acc[2]; st.w = acc[3];
    *(float4*)&out[OUT_OFF + (size_t)b * C_ * F_ + l15 * F_ + j0 + lg * 4] = st;
  }
}

// ============ Kernel B: adj pooling, 2 GRAPHS PER BLOCK (latency amortization) ============
__launch_bounds__(512, 4)
__global__ void pool2_kernel(
    const float* __restrict__ adj, const float* __restrict__ s, const float* __restrict__ pos,
    float* __restrict__ out, double* __restrict__ partials)
{
  __shared__ __align__(16) short AdjA[80 * 128], AdjB2[80 * 128];  // adj bf16 per graph
  __shared__ __align__(16) short ssmA[16 * 128], ssmB[16 * 128];
  __shared__ __align__(16) short TTA[16 * 128],  TTB[16 * 128];
  __shared__ double red[32];

  const int blk = blockIdx.x, tid = threadIdx.x;
  const int gA = blk * 2, gB = blk * 2 + 1;
  const int lane = tid & 63, wave = tid >> 6;
  const int l15 = lane & 15, lg = lane >> 4;

  // ---- P0: zero pads + float4 adj loads + softmax (both graphs) + pos ----
  {
    long long z8 = 0;
    for (int i = tid; i < 1200; i += 512) {          // cols [68,128), rows 0-79
      int r = i / 15, cb = 136 + (i % 15) * 8;
      *(long long*)((char*)AdjA + SWZ256(r, cb)) = z8;
      *(long long*)((char*)AdjB2 + SWZ256(r, cb)) = z8;
    }
    for (int i = tid; i < 204; i += 512) {           // rows 68-79, cols [0,68)
      int r = 68 + i / 17, cb = (i % 17) * 8;
      *(long long*)((char*)AdjA + SWZ256(r, cb)) = z8;
      *(long long*)((char*)AdjB2 + SWZ256(r, cb)) = z8;
    }
    for (int i = tid; i < 112; i += 512) {           // ssm/TT cols [68,96)
      int r = i / 7, cb = 136 + (i % 7) * 8;
      *(long long*)((char*)ssmA + SWZ256(r, cb)) = z8;
      *(long long*)((char*)ssmB + SWZ256(r, cb)) = z8;
      *(long long*)((char*)TTA + SWZ256(r, cb)) = z8;
      *(long long*)((char*)TTB + SWZ256(r, cb)) = z8;
    }
  }
  // adj: 68*68 = 4624 floats = 1156 float4 (rows = 17 float4 exactly, never straddle)
  float sadjA = 0.f, sadjB = 0.f;
  const float* adjbA = &adj[(size_t)gA * N_ * N_];
  const float* adjbB = &adj[(size_t)gB * N_ * N_];
#pragma unroll
  for (int i = 0; i < 3; ++i) {
    int q4 = tid + 512 * i;
    if (q4 < 1156) {
      float4 vA = *(const float4*)&adjbA[q4 * 4];
      float4 vB = *(const float4*)&adjbB[q4 * 4];
      sadjA += vA.x * vA.x + vA.y * vA.y + vA.z * vA.z + vA.w * vA.w;
      sadjB += vB.x * vB.x + vB.y * vB.y + vB.z * vB.z + vB.w * vB.w;
      int n = q4 / 17, m4 = (q4 - n * 17) * 4;
      f32x4 fa; fa[0] = vA.x; fa[1] = vA.y; fa[2] = vA.z; fa[3] = vA.w;
      f32x4 fb; fb[0] = vB.x; fb[1] = vB.y; fb[2] = vB.z; fb[3] = vB.w;
      *(short4*)((char*)AdjA + SWZ256(n, m4 * 2)) = pack4(fa);
      *(short4*)((char*)AdjB2 + SWZ256(n, m4 * 2)) = pack4(fb);
    }
  }
  // softmax: threads [0,68) -> graph A, threads [128,196) -> graph B (separate waves)
  float entA = 0.f, entB = 0.f;
  {
    bool isA = (tid < N_);
    bool isB = (tid >= 128 && tid < 128 + N_);
    if (isA || isB) {
      int row = isB ? (tid - 128) : tid;
      const float* srow = &s[((size_t)(isB ? gB : gA) * N_ + row) * C_];
      short* ssmP = isB ? ssmB : ssmA;
      float sv[16], ev[16];
      float mx = -1e30f;
#pragma unroll
      for (int c = 0; c < 16; ++c) { sv[c] = srow[c]; mx = fmaxf(mx, sv[c]); }
      float sum = 0.f;
#pragma unroll
      for (int c = 0; c < 16; ++c) { ev[c] = expf(sv[c] - mx); sum += ev[c]; }
      float inv = 1.f / sum, ps = 0.f;
#pragma unroll
      for (int c = 0; c < 16; ++c) {
        float pv = ev[c] * inv;
        ps += pv * sv[c];
        *(short*)((char*)ssmP + SWZ256(c, row * 2)) = bf16_rne(pv);
      }
      float ent = (mx + logf(sum)) - ps;
      if (isB) entB = ent; else entA = ent;
    }
  }
  for (int i = tid; i < N_ * FIN; i += 512) {
    out[POS_OFF + (size_t)gA * N_ * FIN + i] = pos[(size_t)gA * N_ * FIN + i];
    out[POS_OFF + (size_t)gB * N_ * FIN + i] = pos[(size_t)gB * N_ * FIN + i];
  }
  __syncthreads();

  // ---- P1: T = adj@S for both graphs (waves 0-4); G = S^T S both (wave 5) ----
  float g2A = 0.f, g2B = 0.f;
  if (wave < 5) {
    f32x4 accA = {0.f, 0.f, 0.f, 0.f};
    f32x4 accB = {0.f, 0.f, 0.f, 0.f};
#pragma unroll
    for (int ks = 0; ks < 3; ++ks) {
      accA = MFMA16(*(const bf16x8*)((const char*)AdjA + SWZ256(wave * 16 + l15, ks * 64 + 16 * lg)),
                    *(const bf16x8*)((const char*)ssmA + SWZ256(l15, ks * 64 + 16 * lg)), accA);
      accB = MFMA16(*(const bf16x8*)((const char*)AdjB2 + SWZ256(wave * 16 + l15, ks * 64 + 16 * lg)),
                    *(const bf16x8*)((const char*)ssmB + SWZ256(l15, ks * 64 + 16 * lg)), accB);
    }
#pragma unroll
    for (int r = 0; r < 4; ++r) {
      int n = wave * 16 + lg * 4 + r;
      if (n < N_) {
        *(short*)((char*)TTA + SWZ256(l15, n * 2)) = bf16_rne(accA[r]);
        *(short*)((char*)TTB + SWZ256(l15, n * 2)) = bf16_rne(accB[r]);
      }
    }
  } else if (wave == 5) {
    f32x4 accA = {0.f, 0.f, 0.f, 0.f};
    f32x4 accB = {0.f, 0.f, 0.f, 0.f};
#pragma unroll
    for (int ks = 0; ks < 3; ++ks) {
      bf16x8 a = *(const bf16x8*)((const char*)ssmA + SWZ256(l15, ks * 64 + 16 * lg));
      bf16x8 b = *(const bf16x8*)((const char*)ssmB + SWZ256(l15, ks * 64 + 16 * lg));
      accA = MFMA16(a, a, accA);
      accB = MFMA16(b, b, accB);
    }
#pragma unroll
    for (int r = 0; r < 4; ++r) { g2A += accA[r] * accA[r]; g2B += accB[r] * accB[r]; }
  }
  __syncthreads();

  // ---- P2: out_adj = S^T T — wave 0 graph A, wave 1 graph B (parallel) ----
  float trA = 0.f, trB = 0.f;
  if (wave == 0) {
    f32x4 acc = {0.f, 0.f, 0.f, 0.f};
#pragma unroll
    for (int ks = 0; ks < 3; ++ks)
      acc = MFMA16(*(const bf16x8*)((const char*)ssmA + SWZ256(l15, ks * 64 + 16 * lg)),
                   *(const bf16x8*)((const char*)TTA + SWZ256(l15, ks * 64 + 16 * lg)), acc);
#pragma unroll
    for (int r = 0; r < 4; ++r) {
      int c = lg * 4 + r;
      out[ADJ_OFF + (size_t)gA * 256 + c * 16 + l15] = acc[r];
      if (c == l15) trA += acc[r];
    }
  } else if (wave == 1) {
    f32x4 acc = {0.f, 0.f, 0.f, 0.f};
#pragma unroll
    for (int ks = 0; ks < 3; ++ks)
      acc = MFMA16(*(const bf16x8*)((const char*)ssmB + SWZ256(l15, ks * 64 + 16 * lg)),
                   *(const bf16x8*)((const char*)TTB + SWZ256(l15, ks * 64 + 16 * lg)), acc);
#pragma unroll
    for (int r = 0; r < 4; ++r) {
      int c = lg * 4 + r;
      out[ADJ_OFF + (size_t)gB * 256 + c * 16 + l15] = acc[r];
      if (c == l15) trB += acc[r];
    }
  }

  // ---- P3: losses, both graphs ----
  double lkA = (double)sadjA - 2.0 * (double)trA + (double)g2A;
  double lkB = (double)sadjB - 2.0 * (double)trB + (double)g2B;
  double enA = (double)entA, enB = (double)entB;
  for (int o = 32; o > 0; o >>= 1) {
    lkA += __shfl_down(lkA, o); enA += __shfl_down(enA, o);
    lkB += __shfl_down(lkB, o); enB += __shfl_down(enB, o);
  }
  if ((tid & 63) == 0) {
    red[wave] = lkA; red[8 + wave] = enA;
    red[16 + wave] = lkB; red[24 + wave] = enB;
  }
  __syncthreads();
  if (tid == 0) {
    double LA = 0, EA = 0, LB = 0, EB = 0;
    for (int w = 0; w < 8; ++w) {
      LA += red[w]; EA += red[8 + w];
      LB += red[16 + w]; EB += red[24 + w];
    }
    partials[2 * gA] = LA; partials[2 * gA + 1] = EA;
    partials[2 * gB] = LB; partials[2 * gB + 1] = EB;
  }
}

__global__ void finalize_kernel(const double* __restrict__ partials, float* __restrict__ out) {
  __shared__ double red[16];
  int tid = threadIdx.x;
  double L = 0, En = 0;
  for (int i = tid; i < B_; i += 512) { L += partials[2 * i]; En += partials[2 * i + 1]; }
  for (int o = 32; o > 0; o >>= 1) { L += __shfl_down(L, o); En += __shfl_down(En, o); }
  if ((tid & 63) == 0) { red[tid >> 6] = L; red[8 + (tid >> 6)] = En; }
  __syncthreads();
  if (tid == 0) {
    double Ls = 0, Es = 0;
    for (int w = 0; w < 8; ++w) { Ls += red[w]; Es += red[8 + w]; }
    out[LINK_IDX] = (float)(sqrt(Ls) / (double)((size_t)B_ * N_ * N_));
    out[ENT_IDX] = (float)(Es / (double)((size_t)B_ * N_));
  }
}

extern "C" void kernel_launch(void* const* d_in, const int* in_sizes, int n_in,
                              void* d_out, int out_size, void* d_ws, size_t ws_size,
                              hipStream_t stream) {
  const float* x   = (const float*)d_in[0];
  const int*   ei  = (const int*)d_in[1];
  const float* adj = (const float*)d_in[2];
  const float* s   = (const float*)d_in[3];
  const float* pos = (const float*)d_in[4];
  const float* W1r = (const float*)d_in[5];
  const float* W1o = (const float*)d_in[6];
  const float* b1  = (const float*)d_in[7];
  const float* W2r = (const float*)d_in[8];
  const float* W2o = (const float*)d_in[9];
  const float* b2  = (const float*)d_in[10];
  const float* W3r = (const float*)d_in[11];
  const float* W3o = (const float*)d_in[12];
  const float* b3  = (const float*)d_in[13];

  float* out = (float*)d_out;
  double* partials = (double*)d_ws;
  int* csr = (int*)((char*)d_ws + WS_CSR_OFF);
  short* wcat = (short*)((char*)d_ws + WS_W_OFF);
  short* agw  = (short*)((char*)d_ws + WS_AG_OFF);

  prep_kernel<<<65, 512, 0, stream>>>(ei, W2r, W2o, W3r, W3o, csr, wcat, agw);
  layers_kernel<<<B_, 512, 0, stream>>>(x, s, W1r, W1o, b1, b2, b3, wcat, agw, out, csr);
  pool2_kernel<<<B_ / 2, 512, 0, stream>>>(adj, s, pos, out, partials);
  finalize_kernel<<<1, 512, 0, stream>>>(partials, out);
}